// Round 8
// baseline (254.320 us; speedup 1.0000x reference)
//
#include <hip/hip_runtime.h>
#include <math.h>

// FourierCrossAttention: B=16, L=4096, H=8, E=EO=64, MODES=64 (lowest)
// R8: k1 is concurrency-limited (1.5 TB/s with all pipes idle; R4==R6==R7).
// Fix: 2-iteration-deep x-prefetch in two STATIC register sets (rsA/rsB,
// loop unrolled x2) so the rs-use waitcnt never waits on a load younger
// than 2 iterations. A-loads stay at iter top (L2, covered by convert+
// barrier). lds-only barrier kept. Same accumulation order -> bit-identical.

constexpr float TWOPI_L = 1.5339807878856412e-3f;  // 2*pi/4096

typedef __attribute__((ext_vector_type(8))) short short8;
typedef __attribute__((ext_vector_type(4))) float f32x4;

__device__ __forceinline__ unsigned short f2bf(float f) {
    unsigned int u = __builtin_bit_cast(unsigned int, f);
    unsigned int r = (u + 0x7fffu + ((u >> 16) & 1u)) >> 16;
    return (unsigned short)r;
}
__device__ __forceinline__ float bf2f(unsigned short h) {
    unsigned int u = ((unsigned int)h) << 16;
    return __builtin_bit_cast(float, u);
}
// packed RNE f32->bf16 pair: low16 = bf(a), high16 = bf(b)
__device__ __forceinline__ unsigned int cvtpk(float a, float b) {
    unsigned int r;
    asm("v_cvt_pk_bf16_f32 %0, %1, %2" : "=v"(r) : "v"(a), "v"(b));
    return r;
}
// workgroup barrier that does NOT drain vmcnt (keeps prefetch in flight)
__device__ __forceinline__ void barrier_lds_only() {
    asm volatile("s_waitcnt lgkmcnt(0)\n\ts_barrier" ::: "memory");
}

// ---------------- K0: DFT twiddle tables (hi/lo bf16) ----------------
__global__ __launch_bounds__(256) void k0_twiddle(unsigned short* __restrict__ Whi,
                                                  unsigned short* __restrict__ Wlo) {
    const int idx = blockIdx.x * 256 + threadIdx.x;   // 131072 threads
    const int r = idx >> 10;            // 0..127
    const int t4 = (idx & 1023) << 2;   // 0..4092
    const int m = r >> 1;
    const bool isim = (r & 1) != 0;
#pragma unroll
    for (int j = 0; j < 4; ++j) {
        const int t = t4 + j;
        float sv, cv;
        sincosf((float)((m * t) & 4095) * TWOPI_L, &sv, &cv);
        const float v = isim ? -sv : cv;
        const unsigned short hi = f2bf(v);
        const unsigned short lo = f2bf(v - bf2f(hi));
        Whi[r * 4096 + t] = hi;
        Wlo[r * 4096 + t] = lo;
    }
}

// ---------------- K0b: irfft basis (bf16 hi only), written into ws (ex-Xq) ----------------
__global__ __launch_bounds__(256) void k0_basis(unsigned short* __restrict__ basis) {
    const int idx = blockIdx.x * 256 + threadIdx.x;   // 65536 threads x 4 pairs
    const int p0 = idx << 2;                          // (t,m) pair index
    const int t = p0 >> 6;
    unsigned int pk[4];
#pragma unroll
    for (int j = 0; j < 4; ++j) {
        const int m = (p0 & 63) + j;
        float sv, cv;
        sincosf((float)((m * t) & 4095) * TWOPI_L, &sv, &cv);
        const float c = (m == 0) ? 1.0f : 2.0f * cv;
        const float s = (m == 0) ? 0.0f : -2.0f * sv;
        pk[j] = (unsigned int)f2bf(c) | ((unsigned int)f2bf(s) << 16);
    }
    *(uint4*)(basis + (size_t)t * 128u + ((p0 & 63) << 1)) =
        make_uint4(pk[0], pk[1], pk[2], pk[3]);
}

// ---------------- K1: MFMA DFT  C[128 rows][64 e], K=512 per block (S=8) ----------------
__global__ __launch_bounds__(256, 4) void k1_mfma(const float* __restrict__ q,
                                                  const float* __restrict__ kin,
                                                  const unsigned short* __restrict__ Whi,
                                                  const unsigned short* __restrict__ Wlo,
                                                  float* __restrict__ Xq, float* __restrict__ Xk,
                                                  float* __restrict__ Pq, float* __restrict__ Pk)
{
    __shared__ unsigned short xTh[2][64][72];   // [buf][e][k pad 64+8] hi
    __shared__ unsigned short xTl[2][64][72];   // lo   (36,864 B total)

    const int tid = threadIdx.x;
    const int bid = blockIdx.x;
    const int bh = bid >> 4, src = (bid >> 3) & 1, seg = bid & 7;
    const int b = bh >> 3, h = bh & 7;
    const float* __restrict__ x = src ? kin : q;
    const float* xb = x + (size_t)b * 2097152u + (size_t)h * 64u + (size_t)(seg * 512) * 512u;

    const int tp = (tid & 31) * 2;
    const int e0 = (tid >> 5) * 8;

    const int wid = tid >> 6, lane = tid & 63;
    const int l15 = lane & 15, lg = lane >> 4;

    const size_t aOff = (size_t)(wid * 32 + l15) * 4096u + (size_t)(seg * 512) + (size_t)(8 * lg);

    f32x4 acc[2][4];
#pragma unroll
    for (int mt = 0; mt < 2; ++mt)
#pragma unroll
        for (int nt = 0; nt < 4; ++nt)
            acc[mt][nt] = (f32x4){0.f, 0.f, 0.f, 0.f};

    float rsA[16], rsB[16];
    {   // prologue: tiles 0 and 1 in flight (2-deep)
        const float* r0 = xb + (size_t)tp * 512u + e0;
        *(float4*)&rsA[0]  = *(const float4*)r0;
        *(float4*)&rsA[4]  = *(const float4*)(r0 + 4);
        *(float4*)&rsA[8]  = *(const float4*)(r0 + 512);
        *(float4*)&rsA[12] = *(const float4*)(r0 + 516);
        const float* r1 = xb + (size_t)(64 + tp) * 512u + e0;
        *(float4*)&rsB[0]  = *(const float4*)r1;
        *(float4*)&rsB[4]  = *(const float4*)(r1 + 4);
        *(float4*)&rsB[8]  = *(const float4*)(r1 + 512);
        *(float4*)&rsB[12] = *(const float4*)(r1 + 516);
    }

    int cur = 0;
#pragma unroll
    for (int itp = 0; itp < 4; ++itp) {
        // ================= even iteration: it = 2*itp, uses rsA =================
        {
            const int it = 2 * itp;
            // A-loads for this iteration (L2-hot; covered by convert+barrier)
            short8 Ah[2][2], Al[2][2];
#pragma unroll
            for (int ks = 0; ks < 2; ++ks)
#pragma unroll
                for (int mt = 0; mt < 2; ++mt) {
                    const size_t o = aOff + (size_t)(mt * 16) * 4096u + (size_t)(it * 64 + ks * 32);
                    Ah[ks][mt] = *(const short8*)(Whi + o);
                    Al[ks][mt] = *(const short8*)(Wlo + o);
                }
            // convert rsA (loaded 2 iterations ago -> retired, no stall)
#pragma unroll
            for (int e = 0; e < 8; ++e) {
                const unsigned int hp = cvtpk(rsA[e], rsA[8 + e]);
                const float h0 = __builtin_bit_cast(float, hp << 16);
                const float h1 = __builtin_bit_cast(float, hp & 0xffff0000u);
                const unsigned int lp = cvtpk(rsA[e] - h0, rsA[8 + e] - h1);
                *(unsigned int*)&xTh[cur][e0 + e][tp] = hp;
                *(unsigned int*)&xTl[cur][e0 + e][tp] = lp;
            }
            // prefetch tile it+2 into rsA (2 iterations of flight time)
            if (it + 2 < 8) {
                const float* r0 = xb + (size_t)((it + 2) * 64 + tp) * 512u + e0;
                *(float4*)&rsA[0]  = *(const float4*)r0;
                *(float4*)&rsA[4]  = *(const float4*)(r0 + 4);
                *(float4*)&rsA[8]  = *(const float4*)(r0 + 512);
                *(float4*)&rsA[12] = *(const float4*)(r0 + 516);
            }
            barrier_lds_only();
#pragma unroll
            for (int ks = 0; ks < 2; ++ks) {
                const unsigned short* sh = &xTh[cur][0][0];
                const unsigned short* sl = &xTl[cur][0][0];
#pragma unroll
                for (int nt = 0; nt < 4; ++nt) {
                    const int ri = (nt * 16 + l15) * 72 + 8 * lg + ks * 32;
                    const short8 Bh = *(const short8*)(sh + ri);
                    const short8 Bl = *(const short8*)(sl + ri);
#pragma unroll
                    for (int mt = 0; mt < 2; ++mt)
                        acc[mt][nt] = __builtin_amdgcn_mfma_f32_16x16x32_bf16(Ah[ks][mt], Bh, acc[mt][nt], 0, 0, 0);
#pragma unroll
                    for (int mt = 0; mt < 2; ++mt)
                        acc[mt][nt] = __builtin_amdgcn_mfma_f32_16x16x32_bf16(Ah[ks][mt], Bl, acc[mt][nt], 0, 0, 0);
#pragma unroll
                    for (int mt = 0; mt < 2; ++mt)
                        acc[mt][nt] = __builtin_amdgcn_mfma_f32_16x16x32_bf16(Al[ks][mt], Bh, acc[mt][nt], 0, 0, 0);
                }
            }
            cur ^= 1;
        }
        // ================= odd iteration: it = 2*itp+1, uses rsB =================
        {
            const int it = 2 * itp + 1;
            short8 Ah[2][2], Al[2][2];
#pragma unroll
            for (int ks = 0; ks < 2; ++ks)
#pragma unroll
                for (int mt = 0; mt < 2; ++mt) {
                    const size_t o = aOff + (size_t)(mt * 16) * 4096u + (size_t)(it * 64 + ks * 32);
                    Ah[ks][mt] = *(const short8*)(Whi + o);
                    Al[ks][mt] = *(const short8*)(Wlo + o);
                }
#pragma unroll
            for (int e = 0; e < 8; ++e) {
                const unsigned int hp = cvtpk(rsB[e], rsB[8 + e]);
                const float h0 = __builtin_bit_cast(float, hp << 16);
                const float h1 = __builtin_bit_cast(float, hp & 0xffff0000u);
                const unsigned int lp = cvtpk(rsB[e] - h0, rsB[8 + e] - h1);
                *(unsigned int*)&xTh[cur][e0 + e][tp] = hp;
                *(unsigned int*)&xTl[cur][e0 + e][tp] = lp;
            }
            if (it + 2 < 8) {
                const float* r0 = xb + (size_t)((it + 2) * 64 + tp) * 512u + e0;
                *(float4*)&rsB[0]  = *(const float4*)r0;
                *(float4*)&rsB[4]  = *(const float4*)(r0 + 4);
                *(float4*)&rsB[8]  = *(const float4*)(r0 + 512);
                *(float4*)&rsB[12] = *(const float4*)(r0 + 516);
            }
            barrier_lds_only();
#pragma unroll
            for (int ks = 0; ks < 2; ++ks) {
                const unsigned short* sh = &xTh[cur][0][0];
                const unsigned short* sl = &xTl[cur][0][0];
#pragma unroll
                for (int nt = 0; nt < 4; ++nt) {
                    const int ri = (nt * 16 + l15) * 72 + 8 * lg + ks * 32;
                    const short8 Bh = *(const short8*)(sh + ri);
                    const short8 Bl = *(const short8*)(sl + ri);
#pragma unroll
                    for (int mt = 0; mt < 2; ++mt)
                        acc[mt][nt] = __builtin_amdgcn_mfma_f32_16x16x32_bf16(Ah[ks][mt], Bh, acc[mt][nt], 0, 0, 0);
#pragma unroll
                    for (int mt = 0; mt < 2; ++mt)
                        acc[mt][nt] = __builtin_amdgcn_mfma_f32_16x16x32_bf16(Ah[ks][mt], Bl, acc[mt][nt], 0, 0, 0);
#pragma unroll
                    for (int mt = 0; mt < 2; ++mt)
                        acc[mt][nt] = __builtin_amdgcn_mfma_f32_16x16x32_bf16(Al[ks][mt], Bh, acc[mt][nt], 0, 0, 0);
                }
            }
            cur ^= 1;
        }
    }

    float* Xd;
    if (seg == 0) Xd = src ? Xk : Xq;
    else          Xd = (src ? Pk : Pq) + (size_t)(seg - 1) * 1048576u;
    Xd += (size_t)bh * 8192u;
#pragma unroll
    for (int mt = 0; mt < 2; ++mt)
#pragma unroll
        for (int nt = 0; nt < 4; ++nt) {
            const int e = nt * 16 + l15;
            const int r0 = wid * 32 + mt * 16 + 4 * lg;
            *(float4*)(Xd + (size_t)e * 128u + r0) = *(float4*)&acc[mt][nt];
        }
}

// ---------------- K1b: reduce the 7 K-split partial sets into main ----------------
__global__ __launch_bounds__(256) void k1_reduce(float* __restrict__ Xq, const float* __restrict__ Pq,
                                                 float* __restrict__ Xk, const float* __restrict__ Pk) {
    const int i = blockIdx.x * 256 + threadIdx.x;   // 262144 float4s per array
    float4* a = (float4*)Xq;
    float4* c = (float4*)Xk;
    float4 v = a[i], w = c[i];
#pragma unroll
    for (int s = 0; s < 7; ++s) {
        const float4 p = ((const float4*)(Pq + (size_t)s * 1048576u))[i];
        const float4 r = ((const float4*)(Pk + (size_t)s * 1048576u))[i];
        v.x += p.x; v.y += p.y; v.z += p.z; v.w += p.w;
        w.x += r.x; w.y += r.y; w.z += r.z; w.w += r.w;
    }
    a[i] = v;
    c[i] = w;
}

// ---------------- K2a: P1  xqk = Xq^T . Xk (complex), tanh -> P[bh][y][2x] ----------------
__global__ __launch_bounds__(256) void k2a_p1(const float* __restrict__ Xq,
                                              const float* __restrict__ Xk,
                                              float* __restrict__ P)
{
    const int blk = blockIdx.x;
    const int bh = blk >> 2, xt = blk & 3;
    __shared__ float sQ[64 * 32];    // [e][2x-slice]
    __shared__ float sK[64 * 128];   // [e][2y]
    const int tid = threadIdx.x;
    const float* Xqb = Xq + (size_t)bh * 8192u;
    const float* Xkb = Xk + (size_t)bh * 8192u;

#pragma unroll
    for (int p = 0; p < 2; ++p) {
        const int f4 = tid + p * 256;           // 512 float4s
        const int row = f4 >> 3, c4 = f4 & 7;
        *(float4*)&sQ[row * 32 + c4 * 4] = *(const float4*)(Xqb + row * 128 + xt * 32 + c4 * 4);
    }
#pragma unroll
    for (int p = 0; p < 8; ++p) {
        const int f4 = tid + p * 256;           // 2048 float4s
        *(float4*)&sK[f4 * 4] = *(const float4*)(Xkb + f4 * 4);
    }
    __syncthreads();

    const int xg = tid & 15, yg = tid >> 4;
    float aR[4] = {0.f, 0.f, 0.f, 0.f}, aI[4] = {0.f, 0.f, 0.f, 0.f};
#pragma unroll 8
    for (int e = 0; e < 64; ++e) {
        const float2 qv = *(const float2*)&sQ[e * 32 + 2 * xg];
        const float4 k0 = *(const float4*)&sK[e * 128 + 8 * yg];
        const float4 k1v = *(const float4*)&sK[e * 128 + 8 * yg + 4];
        aR[0] += qv.x * k0.x - qv.y * k0.y;   aI[0] += qv.x * k0.y + qv.y * k0.x;
        aR[1] += qv.x * k0.z - qv.y * k0.w;   aI[1] += qv.x * k0.w + qv.y * k0.z;
        aR[2] += qv.x * k1v.x - qv.y * k1v.y; aI[2] += qv.x * k1v.y + qv.y * k1v.x;
        aR[3] += qv.x * k1v.z - qv.y * k1v.w; aI[3] += qv.x * k1v.w + qv.y * k1v.z;
    }
    float* Pb = P + (size_t)bh * 8192u;
    const int x_abs = xt * 16 + xg;
#pragma unroll
    for (int j = 0; j < 4; ++j) {
        const int y = 4 * yg + j;
        *(float2*)(Pb + (size_t)y * 128u + 2 * x_abs) =
            make_float2(tanhf(aR[j]), tanhf(aI[j]));
    }
}

// ---------------- K2b: P3  PV = P . Xk (complex over y) -> PVG[h][m][c][b][e] ----------------
__global__ __launch_bounds__(256) void k2b_p3(const float* __restrict__ P,
                                              const float* __restrict__ Xk,
                                              float* __restrict__ PVG)
{
    const int blk = blockIdx.x;
    const int bh = blk >> 2, et = blk & 3;
    const int b = bh >> 3, h = bh & 7;
    __shared__ float sP[64 * 128];   // [y][2x]
    __shared__ float sKe[16 * 132];  // [e_loc][2y] pad->132 (breaks 4-way bank alias)
    const int tid = threadIdx.x;
    const float* Pb = P + (size_t)bh * 8192u;
    const float* Xkb = Xk + (size_t)bh * 8192u + (size_t)(et * 16) * 128u;

#pragma unroll
    for (int p = 0; p < 8; ++p) {
        const int f4 = tid + p * 256;
        *(float4*)&sP[f4 * 4] = *(const float4*)(Pb + f4 * 4);
    }
#pragma unroll
    for (int p = 0; p < 2; ++p) {
        const int f4 = tid + p * 256;           // 512 float4s
        const int row = f4 >> 5, c4 = f4 & 31;
        *(float4*)&sKe[row * 132 + c4 * 4] = *(const float4*)(Xkb + row * 128 + c4 * 4);
    }
    __syncthreads();

    const int xg = tid & 15, el = tid >> 4;
    float aR[4] = {0.f, 0.f, 0.f, 0.f}, aI[4] = {0.f, 0.f, 0.f, 0.f};
#pragma unroll 8
    for (int y = 0; y < 64; ++y) {
        const float2 kv = *(const float2*)&sKe[el * 132 + 2 * y];
        const float4 p0 = *(const float4*)&sP[y * 128 + 8 * xg];
        const float4 p1 = *(const float4*)&sP[y * 128 + 8 * xg + 4];
        aR[0] += p0.x * kv.x - p0.y * kv.y;   aI[0] += p0.x * kv.y + p0.y * kv.x;
        aR[1] += p0.z * kv.x - p0.w * kv.y;   aI[1] += p0.z * kv.y + p0.w * kv.x;
        aR[2] += p1.x * kv.x - p1.y * kv.y;   aI[2] += p1.x * kv.y + p1.y * kv.x;
        aR[3] += p1.z * kv.x - p1.w * kv.y;   aI[3] += p1.z * kv.y + p1.w * kv.x;
    }
    const int e_abs = et * 16 + el;
    float* base = PVG + (size_t)h * 131072u;   // per h: 64m*2c*16b*64e
#pragma unroll
    for (int j = 0; j < 4; ++j) {
        const int m = 4 * xg + j;
        base[(size_t)m * 2048u + 0u    + (size_t)b * 64u + e_abs] = aR[j];
        base[(size_t)m * 2048u + 1024u + (size_t)b * 64u + e_abs] = aI[j];
    }
}

// ---------------- KWT: w1/w2 -> wT[h][m][e][2o] ----------------
__global__ __launch_bounds__(256) void kwt(const float* __restrict__ w1,
                                           const float* __restrict__ w2,
                                           float* __restrict__ wT)
{
    const int blk = blockIdx.x;     // h*64 + e
    const int h = blk >> 6, e = blk & 63;
    const int tid = threadIdx.x;
    const int m = tid & 63, oq = tid >> 6;   // o = oq*16 + i
    const float* w1b = w1 + ((size_t)(h * 64 + e)) * 4096u;
    const float* w2b = w2 + ((size_t)(h * 64 + e)) * 4096u;
    float buf[32];
#pragma unroll
    for (int i = 0; i < 16; ++i) {
        const int o = oq * 16 + i;
        buf[2 * i]     = w1b[o * 64 + m];
        buf[2 * i + 1] = w2b[o * 64 + m];
    }
    float* dst = wT + (((size_t)(h * 64 + m)) * 64u + e) * 128u + oq * 32;
#pragma unroll
    for (int i = 0; i < 8; ++i)
        *(float4*)(dst + i * 4) = *(float4*)&buf[i * 4];
}

// ---------------- K2c: P4  XW = PV . (w1 + i w2) -> XWT hi/lo bf16 ----------------
__global__ __launch_bounds__(256) void k2c_p4(const float* __restrict__ PVG,
                                              const float* __restrict__ wT,
                                              unsigned short* __restrict__ XWThi,
                                              unsigned short* __restrict__ XWTlo)
{
    const int blk = blockIdx.x;       // h*64 + m
    const int h = blk >> 6, m = blk & 63;
    __shared__ float sA[32 * 68];     // [c*16+b][e pad 68]
    __shared__ float sW[64 * 128];    // [e][2o]
    const int tid = threadIdx.x;
    const float* Ab = PVG + (size_t)h * 131072u + (size_t)m * 2048u;
    const float* Wb = wT + ((size_t)h * 64u + m) * 8192u;

#pragma unroll
    for (int p = 0; p < 2; ++p) {
        const int f4 = tid + p * 256;           // 512 float4s
        const int row = f4 >> 4, e0 = (f4 & 15) * 4;
        *(float4*)&sA[row * 68 + e0] = *(const float4*)(Ab + row * 64 + e0);
    }
#pragma unroll
    for (int p = 0; p < 8; ++p) {
        const int f4 = tid + p * 256;
        *(float4*)&sW[f4 * 4] = *(const float4*)(Wb + f4 * 4);
    }
    __syncthreads();

    const int og = tid & 15, b = tid >> 4;
    float aR[4] = {0.f, 0.f, 0.f, 0.f}, aI[4] = {0.f, 0.f, 0.f, 0.f};
#pragma unroll 8
    for (int e = 0; e < 64; ++e) {
        const float pR = sA[b * 68 + e];
        const float pI = sA[(16 + b) * 68 + e];
        const float4 w0 = *(const float4*)&sW[e * 128 + 8 * og];
        const float4 w1v = *(const float4*)&sW[e * 128 + 8 * og + 4];
        aR[0] += pR * w0.x - pI * w0.y;   aI[0] += pR * w0.y + pI * w0.x;
        aR[1] += pR * w0.z - pI * w0.w;   aI[1] += pR * w0.w + pI * w0.z;
        aR[2] += pR * w1v.x - pI * w1v.y; aI[2] += pR * w1v.y + pI * w1v.x;
        aR[3] += pR * w1v.z - pI * w1v.w; aI[3] += pR * w1v.w + pI * w1v.z;
    }
    const int bh = b * 8 + h;
    unsigned short* Th = XWThi + (size_t)bh * 8192u;
    unsigned short* Tl = XWTlo + (size_t)bh * 8192u;
#pragma unroll
    for (int j = 0; j < 4; ++j) {
        const int o = 4 * og + j;
        const unsigned int hp = cvtpk(aR[j], aI[j]);
        const float hR = __builtin_bit_cast(float, hp << 16);
        const float hI = __builtin_bit_cast(float, hp & 0xffff0000u);
        const unsigned int lp = cvtpk(aR[j] - hR, aI[j] - hI);
        *(unsigned int*)(Th + (size_t)o * 128u + 2 * m) = hp;
        *(unsigned int*)(Tl + (size_t)o * 128u + 2 * m) = lp;
    }
}

// ---------------- K3: MFMA irfft  out[4096t x 64o] = basis[4096x128] * XWT^T ----------------
__global__ __launch_bounds__(256, 3) void k3_mfma(const unsigned short* __restrict__ basis,
                                                  const unsigned short* __restrict__ XWThi,
                                                  const unsigned short* __restrict__ XWTlo,
                                                  float* __restrict__ out)
{
    const int bid = blockIdx.x;
    const int bh = bid >> 4, tc = bid & 15;
    const int b = bh >> 3, h = bh & 7;
    const int tid = threadIdx.x;
    const int wid = tid >> 6, lane = tid & 63;
    const int l15 = lane & 15, lg = lane >> 4;

    const int t0 = tc * 256 + wid * 64;
    const unsigned short* Th = XWThi + (size_t)bh * 8192u;
    const unsigned short* Tl = XWTlo + (size_t)bh * 8192u;

    f32x4 acc[4][4];
#pragma unroll
    for (int mt = 0; mt < 4; ++mt)
#pragma unroll
        for (int nt = 0; nt < 4; ++nt)
            acc[mt][nt] = (f32x4){0.f, 0.f, 0.f, 0.f};

#pragma unroll
    for (int ks = 0; ks < 4; ++ks) {
        const int ko = ks * 32 + 8 * lg;
        short8 A[4], Bh[4], Bl[4];
#pragma unroll
        for (int mt = 0; mt < 4; ++mt)
            A[mt] = *(const short8*)(basis + (size_t)(t0 + mt * 16 + l15) * 128u + ko);
#pragma unroll
        for (int nt = 0; nt < 4; ++nt) {
            Bh[nt] = *(const short8*)(Th + (size_t)(nt * 16 + l15) * 128u + ko);
            Bl[nt] = *(const short8*)(Tl + (size_t)(nt * 16 + l15) * 128u + ko);
        }
#pragma unroll
        for (int mt = 0; mt < 4; ++mt)
#pragma unroll
            for (int nt = 0; nt < 4; ++nt)
                acc[mt][nt] = __builtin_amdgcn_mfma_f32_16x16x32_bf16(A[mt], Bh[nt], acc[mt][nt], 0, 0, 0);
#pragma unroll
        for (int mt = 0; mt < 4; ++mt)
#pragma unroll
            for (int nt = 0; nt < 4; ++nt)
                acc[mt][nt] = __builtin_amdgcn_mfma_f32_16x16x32_bf16(A[mt], Bl[nt], acc[mt][nt], 0, 0, 0);
    }

    const float scale = 9.313225746154785e-10f;  // 2^-30
#pragma unroll
    for (int mt = 0; mt < 4; ++mt)
#pragma unroll
        for (int nt = 0; nt < 4; ++nt) {
            const int o = nt * 16 + l15;
#pragma unroll
            for (int j = 0; j < 4; ++j) {
                const int t = t0 + mt * 16 + 4 * lg + j;
                out[((size_t)(b * 4096 + t) * 8u + (size_t)h) * 64u + o] = acc[mt][nt][j] * scale;
            }
        }
}

extern "C" void kernel_launch(void* const* d_in, const int* in_sizes, int n_in,
                              void* d_out, int out_size, void* d_ws, size_t ws_size,
                              hipStream_t stream) {
    (void)in_sizes; (void)n_in; (void)out_size; (void)ws_size;
    const float* q  = (const float*)d_in[0];
    const float* k  = (const float*)d_in[1];
    // d_in[2] = v: unused by the reference forward
    const float* w1 = (const float*)d_in[3];
    const float* w2 = (const float*)d_in[4];
    float* out = (float*)d_out;

    // ws (12 MB): Xq [0,4MB) fl, Xk [4,8MB) fl, XWThi/lo [8,12MB) as bf16
    float* ws = (float*)d_ws;
    float* Xq = ws;
    float* Xk = ws + 1048576;
    unsigned short* XWThi = (unsigned short*)(ws + 2097152);   // 1,048,576 shorts
    unsigned short* XWTlo = XWThi + 1048576;
    unsigned short* basis = (unsigned short*)ws;               // overlays Xq AFTER k2a

    // d_out scratch (33.5M floats; all regions dead before k3 overwrites):
    unsigned short* Whi = (unsigned short*)out;                // [0, 262144) fl
    unsigned short* Wlo = Whi + 524288;                        // [262144, 524288) fl
    float* Pq  = out + 524288;                                 // 7 x 1M fl -> ends 7,864,320
    float* Pk  = out + 7864320;                                // 7 x 1M fl -> ends 15,204,352
    float* P   = out + 16777216;                               // 1M fl  (tanh'd xqk, [y][2x])
    float* wT  = out + 17825792;                               // 4M fl  [h][m][e][2o] -> 22,020,096
    float* PVG = out + 22020096;                               // 1M fl  [h][m][c][b][e]

    hipLaunchKernelGGL(k0_twiddle, dim3(512),  dim3(256), 0, stream, Whi, Wlo);
    hipLaunchKernelGGL(k1_mfma,    dim3(2048), dim3(256), 0, stream, q, k, Whi, Wlo, Xq, Xk, Pq, Pk);
    hipLaunchKernelGGL(k1_reduce,  dim3(1024), dim3(256), 0, stream, Xq, Pq, Xk, Pk);
    hipLaunchKernelGGL(k2a_p1,     dim3(512),  dim3(256), 0, stream, Xq, Xk, P);
    hipLaunchKernelGGL(k0_basis,   dim3(256),  dim3(256), 0, stream, basis);
    hipLaunchKernelGGL(k2b_p3,     dim3(512),  dim3(256), 0, stream, P, Xk, PVG);
    hipLaunchKernelGGL(kwt,        dim3(512),  dim3(256), 0, stream, w1, w2, wT);
    hipLaunchKernelGGL(k2c_p4,     dim3(512),  dim3(256), 0, stream, PVG, wT, XWThi, XWTlo);
    hipLaunchKernelGGL(k3_mfma,    dim3(2048), dim3(256), 0, stream, basis, XWThi, XWTlo, out);
}

// Round 9
// 231.320 us; speedup vs baseline: 1.0994x; 1.0994x over previous
//
#include <hip/hip_runtime.h>
#include <math.h>

// FourierCrossAttention: B=16, L=4096, H=8, E=EO=64, MODES=64 (lowest)
// R9: k1 is VMEM-byte-bound (832MB/dispatch at ~10B/cyc/CU; A-twiddle loads
// are 2x the x bytes and thrash L2). Fix: t/t+2048 fold halves K (A-bytes /2,
// MFMA /2) + fragment-major A-table layout (each A-load = contiguous 1KB).
// Waves 0,1 -> even modes (xp), waves 2,3 -> odd modes (xm).

constexpr float TWOPI_L = 1.5339807878856412e-3f;  // 2*pi/4096

typedef __attribute__((ext_vector_type(8))) short short8;
typedef __attribute__((ext_vector_type(4))) float f32x4;

__device__ __forceinline__ unsigned short f2bf(float f) {
    unsigned int u = __builtin_bit_cast(unsigned int, f);
    unsigned int r = (u + 0x7fffu + ((u >> 16) & 1u)) >> 16;
    return (unsigned short)r;
}
__device__ __forceinline__ float bf2f(unsigned short h) {
    unsigned int u = ((unsigned int)h) << 16;
    return __builtin_bit_cast(float, u);
}
// packed RNE f32->bf16 pair: low16 = bf(a), high16 = bf(b)
__device__ __forceinline__ unsigned int cvtpk(float a, float b) {
    unsigned int r;
    asm("v_cvt_pk_bf16_f32 %0, %1, %2" : "=v"(r) : "v"(a), "v"(b));
    return r;
}
// workgroup barrier that does NOT drain vmcnt
__device__ __forceinline__ void barrier_lds_only() {
    asm volatile("s_waitcnt lgkmcnt(0)\n\ts_barrier" ::: "memory");
}

// ---------------- K0: folded DFT twiddle tables, fragment-major ----------------
// Table rows r_tab = rb*16+l15: 0..63 = even modes (m=2*(r>>1), c=r&1 Re/Im),
// 64..127 = odd modes (m=2*((r-64)>>1)+1). t = kt*32 + lg*8 + j, t<2048.
// Addr = (kt*8 + rb)*512 + l15*32 + lg*8 + j  -> per-MFMA-fragment contiguous.
__global__ __launch_bounds__(256) void k0_twiddle(unsigned short* __restrict__ Whi,
                                                  unsigned short* __restrict__ Wlo) {
    const int idx = blockIdx.x * 256 + threadIdx.x;   // 32768 threads
    const int kt = idx >> 9;            // 0..63
    const int rb = (idx >> 6) & 7;      // 0..7
    const int l15 = (idx >> 2) & 15;    // 0..15
    const int lg = idx & 3;             // 0..3
    const int r_tab = rb * 16 + l15;
    int m, c;
    if (r_tab < 64) { m = (r_tab >> 1) * 2;            c = r_tab & 1; }
    else            { m = (((r_tab - 64) >> 1) * 2) + 1; c = r_tab & 1; }
    const int addr = (kt * 8 + rb) * 512 + l15 * 32 + lg * 8;
    unsigned short hbuf[8], lbuf[8];
#pragma unroll
    for (int j = 0; j < 8; ++j) {
        const int t = kt * 32 + lg * 8 + j;
        float sv, cv;
        sincosf((float)((m * t) & 4095) * TWOPI_L, &sv, &cv);
        const float v = c ? -sv : cv;
        const unsigned short hi = f2bf(v);
        hbuf[j] = hi;
        lbuf[j] = f2bf(v - bf2f(hi));
    }
    *(uint4*)(Whi + addr) = *(uint4*)hbuf;
    *(uint4*)(Wlo + addr) = *(uint4*)lbuf;
}

// ---------------- K0b: irfft basis (bf16 hi only), written into ws (ex-Xq) ----------------
__global__ __launch_bounds__(256) void k0_basis(unsigned short* __restrict__ basis) {
    const int idx = blockIdx.x * 256 + threadIdx.x;   // 65536 threads x 4 pairs
    const int p0 = idx << 2;                          // (t,m) pair index
    const int t = p0 >> 6;
    unsigned int pk[4];
#pragma unroll
    for (int j = 0; j < 4; ++j) {
        const int m = (p0 & 63) + j;
        float sv, cv;
        sincosf((float)((m * t) & 4095) * TWOPI_L, &sv, &cv);
        const float c = (m == 0) ? 1.0f : 2.0f * cv;
        const float s = (m == 0) ? 0.0f : -2.0f * sv;
        pk[j] = (unsigned int)f2bf(c) | ((unsigned int)f2bf(s) << 16);
    }
    *(uint4*)(basis + (size_t)t * 128u + ((p0 & 63) << 1)) =
        make_uint4(pk[0], pk[1], pk[2], pk[3]);
}

// ---------------- K1: folded MFMA DFT. C[128 rows][64 e], K_fold=256/block (S=8) ----------------
__global__ __launch_bounds__(256, 4) void k1_mfma(const float* __restrict__ q,
                                                  const float* __restrict__ kin,
                                                  const unsigned short* __restrict__ Whi,
                                                  const unsigned short* __restrict__ Wlo,
                                                  float* __restrict__ Xq, float* __restrict__ Xk,
                                                  float* __restrict__ Pq, float* __restrict__ Pk)
{
    // [sel: 0=xp_hi 1=xp_lo 2=xm_hi 3=xm_lo][e][f pad 40] -> 20,480 B
    __shared__ unsigned short xT[4][64][40];

    const int tid = threadIdx.x;
    const int bid = blockIdx.x;
    const int bh = bid >> 4, src = (bid >> 3) & 1, seg = bid & 7;
    const int b = bh >> 3, h = bh & 7;
    const float* __restrict__ x = src ? kin : q;
    const float* xb = x + (size_t)b * 2097152u + (size_t)h * 64u;

    // staging map: thread handles f-pair (fp,fp+1), 4 e's
    const int fp = (tid & 15) * 2;
    const int e0s = (tid >> 4) * 4;

    const int wid = tid >> 6, lane = tid & 63;
    const int l15 = lane & 15, lg = lane >> 4;
    const int aoffL = l15 * 32 + lg * 8;
    const int sel = (wid >> 1) * 2;       // waves 0,1: xp; waves 2,3: xm

    f32x4 acc[2][4];
#pragma unroll
    for (int mt = 0; mt < 2; ++mt)
#pragma unroll
        for (int nt = 0; nt < 4; ++nt)
            acc[mt][nt] = (f32x4){0.f, 0.f, 0.f, 0.f};

    for (int it = 0; it < 8; ++it) {
        const int t0 = seg * 256 + it * 32;     // raw t base (folded range)
        // raw x loads: rows t0+fp, t0+fp+1 and +2048 counterparts
        float rs[16];
        {
            const float* r0 = xb + (size_t)(t0 + fp) * 512u + e0s;
            *(f32x4*)&rs[0]  = *(const f32x4*)r0;
            *(f32x4*)&rs[4]  = *(const f32x4*)(r0 + 512);
            *(f32x4*)&rs[8]  = *(const f32x4*)(r0 + 2048 * 512);
            *(f32x4*)&rs[12] = *(const f32x4*)(r0 + 2048 * 512 + 512);
        }
        // A-loads (fragment-major: contiguous 16B/lane, 1KB/instruction)
        short8 Ah[2], Al[2];
#pragma unroll
        for (int mt = 0; mt < 2; ++mt) {
            const size_t o = (size_t)(((seg * 8 + it) * 8 + (wid * 2 + mt)) * 512 + aoffL);
            Ah[mt] = *(const short8*)(Whi + o);
            Al[mt] = *(const short8*)(Wlo + o);
        }
        // fold + convert -> LDS
#pragma unroll
        for (int ee = 0; ee < 4; ++ee) {
            const float a0 = rs[ee], a1 = rs[4 + ee];
            const float c0 = rs[8 + ee], c1 = rs[12 + ee];
            const float xp0 = a0 + c0, xp1 = a1 + c1;
            const float xm0 = a0 - c0, xm1 = a1 - c1;
            const int e = e0s + ee;
            const unsigned int php = cvtpk(xp0, xp1);
            const float ph0 = __builtin_bit_cast(float, php << 16);
            const float ph1 = __builtin_bit_cast(float, php & 0xffff0000u);
            const unsigned int plp = cvtpk(xp0 - ph0, xp1 - ph1);
            const unsigned int mhp = cvtpk(xm0, xm1);
            const float mh0 = __builtin_bit_cast(float, mhp << 16);
            const float mh1 = __builtin_bit_cast(float, mhp & 0xffff0000u);
            const unsigned int mlp = cvtpk(xm0 - mh0, xm1 - mh1);
            *(unsigned int*)&xT[0][e][fp] = php;
            *(unsigned int*)&xT[1][e][fp] = plp;
            *(unsigned int*)&xT[2][e][fp] = mhp;
            *(unsigned int*)&xT[3][e][fp] = mlp;
        }
        barrier_lds_only();   // staged tile visible

        const unsigned short* sh = &xT[sel][0][0];
        const unsigned short* sl = &xT[sel + 1][0][0];
#pragma unroll
        for (int nt = 0; nt < 4; ++nt) {
            const int ri = (nt * 16 + l15) * 40 + 8 * lg;
            const short8 Bh = *(const short8*)(sh + ri);
            const short8 Bl = *(const short8*)(sl + ri);
#pragma unroll
            for (int mt = 0; mt < 2; ++mt)
                acc[mt][nt] = __builtin_amdgcn_mfma_f32_16x16x32_bf16(Ah[mt], Bh, acc[mt][nt], 0, 0, 0);
#pragma unroll
            for (int mt = 0; mt < 2; ++mt)
                acc[mt][nt] = __builtin_amdgcn_mfma_f32_16x16x32_bf16(Ah[mt], Bl, acc[mt][nt], 0, 0, 0);
#pragma unroll
            for (int mt = 0; mt < 2; ++mt)
                acc[mt][nt] = __builtin_amdgcn_mfma_f32_16x16x32_bf16(Al[mt], Bh, acc[mt][nt], 0, 0, 0);
        }
        barrier_lds_only();   // reads done before next iteration's writes
    }

    // C-write. Even waves (wid<2): mode m=2*jm -> X rows 4*jm+{0,1};
    // odd waves: m=2*jm+1 -> X rows 4*jm+{2,3}. jm = (wid*2+mt)*8 + 2*lg + (jj>>1) (mod half).
    float* Xd;
    if (seg == 0) Xd = src ? Xk : Xq;
    else          Xd = (src ? Pk : Pq) + (size_t)(seg - 1) * 1048576u;
    Xd += (size_t)bh * 8192u;
    const int oddw = wid >> 1;
    const int wb = wid & 1;
#pragma unroll
    for (int mt = 0; mt < 2; ++mt) {
        const int r0 = (wb * 2 + mt) * 32 + 8 * lg + 2 * oddw;
#pragma unroll
        for (int nt = 0; nt < 4; ++nt) {
            const int e = nt * 16 + l15;
            *(float2*)(Xd + (size_t)e * 128u + r0) =
                make_float2(acc[mt][nt][0], acc[mt][nt][1]);
            *(float2*)(Xd + (size_t)e * 128u + r0 + 4) =
                make_float2(acc[mt][nt][2], acc[mt][nt][3]);
        }
    }
}

// ---------------- K1b: reduce the 7 K-split partial sets into main ----------------
__global__ __launch_bounds__(256) void k1_reduce(float* __restrict__ Xq, const float* __restrict__ Pq,
                                                 float* __restrict__ Xk, const float* __restrict__ Pk) {
    const int i = blockIdx.x * 256 + threadIdx.x;   // 262144 float4s per array
    float4* a = (float4*)Xq;
    float4* c = (float4*)Xk;
    float4 v = a[i], w = c[i];
#pragma unroll
    for (int s = 0; s < 7; ++s) {
        const float4 p = ((const float4*)(Pq + (size_t)s * 1048576u))[i];
        const float4 r = ((const float4*)(Pk + (size_t)s * 1048576u))[i];
        v.x += p.x; v.y += p.y; v.z += p.z; v.w += p.w;
        w.x += r.x; w.y += r.y; w.z += r.z; w.w += r.w;
    }
    a[i] = v;
    c[i] = w;
}

// ---------------- K2a: P1  xqk = Xq^T . Xk (complex), tanh -> P[bh][y][2x] ----------------
__global__ __launch_bounds__(256) void k2a_p1(const float* __restrict__ Xq,
                                              const float* __restrict__ Xk,
                                              float* __restrict__ P)
{
    const int blk = blockIdx.x;
    const int bh = blk >> 2, xt = blk & 3;
    __shared__ float sQ[64 * 32];    // [e][2x-slice]
    __shared__ float sK[64 * 128];   // [e][2y]
    const int tid = threadIdx.x;
    const float* Xqb = Xq + (size_t)bh * 8192u;
    const float* Xkb = Xk + (size_t)bh * 8192u;

#pragma unroll
    for (int p = 0; p < 2; ++p) {
        const int f4 = tid + p * 256;           // 512 float4s
        const int row = f4 >> 3, c4 = f4 & 7;
        *(float4*)&sQ[row * 32 + c4 * 4] = *(const float4*)(Xqb + row * 128 + xt * 32 + c4 * 4);
    }
#pragma unroll
    for (int p = 0; p < 8; ++p) {
        const int f4 = tid + p * 256;           // 2048 float4s
        *(float4*)&sK[f4 * 4] = *(const float4*)(Xkb + f4 * 4);
    }
    __syncthreads();

    const int xg = tid & 15, yg = tid >> 4;
    float aR[4] = {0.f, 0.f, 0.f, 0.f}, aI[4] = {0.f, 0.f, 0.f, 0.f};
#pragma unroll 8
    for (int e = 0; e < 64; ++e) {
        const float2 qv = *(const float2*)&sQ[e * 32 + 2 * xg];
        const float4 k0 = *(const float4*)&sK[e * 128 + 8 * yg];
        const float4 k1v = *(const float4*)&sK[e * 128 + 8 * yg + 4];
        aR[0] += qv.x * k0.x - qv.y * k0.y;   aI[0] += qv.x * k0.y + qv.y * k0.x;
        aR[1] += qv.x * k0.z - qv.y * k0.w;   aI[1] += qv.x * k0.w + qv.y * k0.z;
        aR[2] += qv.x * k1v.x - qv.y * k1v.y; aI[2] += qv.x * k1v.y + qv.y * k1v.x;
        aR[3] += qv.x * k1v.z - qv.y * k1v.w; aI[3] += qv.x * k1v.w + qv.y * k1v.z;
    }
    float* Pb = P + (size_t)bh * 8192u;
    const int x_abs = xt * 16 + xg;
#pragma unroll
    for (int j = 0; j < 4; ++j) {
        const int y = 4 * yg + j;
        *(float2*)(Pb + (size_t)y * 128u + 2 * x_abs) =
            make_float2(tanhf(aR[j]), tanhf(aI[j]));
    }
}

// ---------------- K2b: P3  PV = P . Xk (complex over y) -> PVG[h][m][c][b][e] ----------------
__global__ __launch_bounds__(256) void k2b_p3(const float* __restrict__ P,
                                              const float* __restrict__ Xk,
                                              float* __restrict__ PVG)
{
    const int blk = blockIdx.x;
    const int bh = blk >> 2, et = blk & 3;
    const int b = bh >> 3, h = bh & 7;
    __shared__ float sP[64 * 128];   // [y][2x]
    __shared__ float sKe[16 * 132];  // [e_loc][2y] pad->132
    const int tid = threadIdx.x;
    const float* Pb = P + (size_t)bh * 8192u;
    const float* Xkb = Xk + (size_t)bh * 8192u + (size_t)(et * 16) * 128u;

#pragma unroll
    for (int p = 0; p < 8; ++p) {
        const int f4 = tid + p * 256;
        *(float4*)&sP[f4 * 4] = *(const float4*)(Pb + f4 * 4);
    }
#pragma unroll
    for (int p = 0; p < 2; ++p) {
        const int f4 = tid + p * 256;           // 512 float4s
        const int row = f4 >> 5, c4 = f4 & 31;
        *(float4*)&sKe[row * 132 + c4 * 4] = *(const float4*)(Xkb + row * 128 + c4 * 4);
    }
    __syncthreads();

    const int xg = tid & 15, el = tid >> 4;
    float aR[4] = {0.f, 0.f, 0.f, 0.f}, aI[4] = {0.f, 0.f, 0.f, 0.f};
#pragma unroll 8
    for (int y = 0; y < 64; ++y) {
        const float2 kv = *(const float2*)&sKe[el * 132 + 2 * y];
        const float4 p0 = *(const float4*)&sP[y * 128 + 8 * xg];
        const float4 p1 = *(const float4*)&sP[y * 128 + 8 * xg + 4];
        aR[0] += p0.x * kv.x - p0.y * kv.y;   aI[0] += p0.x * kv.y + p0.y * kv.x;
        aR[1] += p0.z * kv.x - p0.w * kv.y;   aI[1] += p0.z * kv.y + p0.w * kv.x;
        aR[2] += p1.x * kv.x - p1.y * kv.y;   aI[2] += p1.x * kv.y + p1.y * kv.x;
        aR[3] += p1.z * kv.x - p1.w * kv.y;   aI[3] += p1.z * kv.y + p1.w * kv.x;
    }
    const int e_abs = et * 16 + el;
    float* base = PVG + (size_t)h * 131072u;   // per h: 64m*2c*16b*64e
#pragma unroll
    for (int j = 0; j < 4; ++j) {
        const int m = 4 * xg + j;
        base[(size_t)m * 2048u + 0u    + (size_t)b * 64u + e_abs] = aR[j];
        base[(size_t)m * 2048u + 1024u + (size_t)b * 64u + e_abs] = aI[j];
    }
}

// ---------------- KWT: w1/w2 -> wT[h][m][e][2o] ----------------
__global__ __launch_bounds__(256) void kwt(const float* __restrict__ w1,
                                           const float* __restrict__ w2,
                                           float* __restrict__ wT)
{
    const int blk = blockIdx.x;     // h*64 + e
    const int h = blk >> 6, e = blk & 63;
    const int tid = threadIdx.x;
    const int m = tid & 63, oq = tid >> 6;   // o = oq*16 + i
    const float* w1b = w1 + ((size_t)(h * 64 + e)) * 4096u;
    const float* w2b = w2 + ((size_t)(h * 64 + e)) * 4096u;
    float buf[32];
#pragma unroll
    for (int i = 0; i < 16; ++i) {
        const int o = oq * 16 + i;
        buf[2 * i]     = w1b[o * 64 + m];
        buf[2 * i + 1] = w2b[o * 64 + m];
    }
    float* dst = wT + (((size_t)(h * 64 + m)) * 64u + e) * 128u + oq * 32;
#pragma unroll
    for (int i = 0; i < 8; ++i)
        *(float4*)(dst + i * 4) = *(float4*)&buf[i * 4];
}

// ---------------- K2c: P4  XW = PV . (w1 + i w2) -> XWT hi/lo bf16 ----------------
__global__ __launch_bounds__(256) void k2c_p4(const float* __restrict__ PVG,
                                              const float* __restrict__ wT,
                                              unsigned short* __restrict__ XWThi,
                                              unsigned short* __restrict__ XWTlo)
{
    const int blk = blockIdx.x;       // h*64 + m
    const int h = blk >> 6, m = blk & 63;
    __shared__ float sA[32 * 68];     // [c*16+b][e pad 68]
    __shared__ float sW[64 * 128];    // [e][2o]
    const int tid = threadIdx.x;
    const float* Ab = PVG + (size_t)h * 131072u + (size_t)m * 2048u;
    const float* Wb = wT + ((size_t)h * 64u + m) * 8192u;

#pragma unroll
    for (int p = 0; p < 2; ++p) {
        const int f4 = tid + p * 256;           // 512 float4s
        const int row = f4 >> 4, e0 = (f4 & 15) * 4;
        *(float4*)&sA[row * 68 + e0] = *(const float4*)(Ab + row * 64 + e0);
    }
#pragma unroll
    for (int p = 0; p < 8; ++p) {
        const int f4 = tid + p * 256;
        *(float4*)&sW[f4 * 4] = *(const float4*)(Wb + f4 * 4);
    }
    __syncthreads();

    const int og = tid & 15, b = tid >> 4;
    float aR[4] = {0.f, 0.f, 0.f, 0.f}, aI[4] = {0.f, 0.f, 0.f, 0.f};
#pragma unroll 8
    for (int e = 0; e < 64; ++e) {
        const float pR = sA[b * 68 + e];
        const float pI = sA[(16 + b) * 68 + e];
        const float4 w0 = *(const float4*)&sW[e * 128 + 8 * og];
        const float4 w1v = *(const float4*)&sW[e * 128 + 8 * og + 4];
        aR[0] += pR * w0.x - pI * w0.y;   aI[0] += pR * w0.y + pI * w0.x;
        aR[1] += pR * w0.z - pI * w0.w;   aI[1] += pR * w0.w + pI * w0.z;
        aR[2] += pR * w1v.x - pI * w1v.y; aI[2] += pR * w1v.y + pI * w1v.x;
        aR[3] += pR * w1v.z - pI * w1v.w; aI[3] += pR * w1v.w + pI * w1v.z;
    }
    const int bh = b * 8 + h;
    unsigned short* Th = XWThi + (size_t)bh * 8192u;
    unsigned short* Tl = XWTlo + (size_t)bh * 8192u;
#pragma unroll
    for (int j = 0; j < 4; ++j) {
        const int o = 4 * og + j;
        const unsigned int hp = cvtpk(aR[j], aI[j]);
        const float hR = __builtin_bit_cast(float, hp << 16);
        const float hI = __builtin_bit_cast(float, hp & 0xffff0000u);
        const unsigned int lp = cvtpk(aR[j] - hR, aI[j] - hI);
        *(unsigned int*)(Th + (size_t)o * 128u + 2 * m) = hp;
        *(unsigned int*)(Tl + (size_t)o * 128u + 2 * m) = lp;
    }
}

// ---------------- K3: MFMA irfft  out[4096t x 64o] = basis[4096x128] * XWT^T ----------------
__global__ __launch_bounds__(256, 3) void k3_mfma(const unsigned short* __restrict__ basis,
                                                  const unsigned short* __restrict__ XWThi,
                                                  const unsigned short* __restrict__ XWTlo,
                                                  float* __restrict__ out)
{
    const int bid = blockIdx.x;
    const int bh = bid >> 4, tc = bid & 15;
    const int b = bh >> 3, h = bh & 7;
    const int tid = threadIdx.x;
    const int wid = tid >> 6, lane = tid & 63;
    const int l15 = lane & 15, lg = lane >> 4;

    const int t0 = tc * 256 + wid * 64;
    const unsigned short* Th = XWThi + (size_t)bh * 8192u;
    const unsigned short* Tl = XWTlo + (size_t)bh * 8192u;

    f32x4 acc[4][4];
#pragma unroll
    for (int mt = 0; mt < 4; ++mt)
#pragma unroll
        for (int nt = 0; nt < 4; ++nt)
            acc[mt][nt] = (f32x4){0.f, 0.f, 0.f, 0.f};

#pragma unroll
    for (int ks = 0; ks < 4; ++ks) {
        const int ko = ks * 32 + 8 * lg;
        short8 A[4], Bh[4], Bl[4];
#pragma unroll
        for (int mt = 0; mt < 4; ++mt)
            A[mt] = *(const short8*)(basis + (size_t)(t0 + mt * 16 + l15) * 128u + ko);
#pragma unroll
        for (int nt = 0; nt < 4; ++nt) {
            Bh[nt] = *(const short8*)(Th + (size_t)(nt * 16 + l15) * 128u + ko);
            Bl[nt] = *(const short8*)(Tl + (size_t)(nt * 16 + l15) * 128u + ko);
        }
#pragma unroll
        for (int mt = 0; mt < 4; ++mt)
#pragma unroll
            for (int nt = 0; nt < 4; ++nt)
                acc[mt][nt] = __builtin_amdgcn_mfma_f32_16x16x32_bf16(A[mt], Bh[nt], acc[mt][nt], 0, 0, 0);
#pragma unroll
        for (int mt = 0; mt < 4; ++mt)
#pragma unroll
            for (int nt = 0; nt < 4; ++nt)
                acc[mt][nt] = __builtin_amdgcn_mfma_f32_16x16x32_bf16(A[mt], Bl[nt], acc[mt][nt], 0, 0, 0);
    }

    const float scale = 9.313225746154785e-10f;  // 2^-30
#pragma unroll
    for (int mt = 0; mt < 4; ++mt)
#pragma unroll
        for (int nt = 0; nt < 4; ++nt) {
            const int o = nt * 16 + l15;
#pragma unroll
            for (int j = 0; j < 4; ++j) {
                const int t = t0 + mt * 16 + 4 * lg + j;
                out[((size_t)(b * 4096 + t) * 8u + (size_t)h) * 64u + o] = acc[mt][nt][j] * scale;
            }
        }
}

extern "C" void kernel_launch(void* const* d_in, const int* in_sizes, int n_in,
                              void* d_out, int out_size, void* d_ws, size_t ws_size,
                              hipStream_t stream) {
    (void)in_sizes; (void)n_in; (void)out_size; (void)ws_size;
    const float* q  = (const float*)d_in[0];
    const float* k  = (const float*)d_in[1];
    // d_in[2] = v: unused by the reference forward
    const float* w1 = (const float*)d_in[3];
    const float* w2 = (const float*)d_in[4];
    float* out = (float*)d_out;

    // ws (12 MB): Xq [0,4MB) fl, Xk [4,8MB) fl, XWThi/lo [8,12MB) as bf16
    float* ws = (float*)d_ws;
    float* Xq = ws;
    float* Xk = ws + 1048576;
    unsigned short* XWThi = (unsigned short*)(ws + 2097152);   // 1,048,576 shorts
    unsigned short* XWTlo = XWThi + 1048576;
    unsigned short* basis = (unsigned short*)ws;               // overlays Xq AFTER k2a

    // d_out scratch (33.5M floats; all regions dead before k3 overwrites):
    unsigned short* Whi = (unsigned short*)out;                // 262,144 shorts (folded table)
    unsigned short* Wlo = Whi + 262144;                        // 262,144 shorts
    float* Pq  = out + 524288;                                 // 7 x 1M fl -> ends 7,864,320
    float* Pk  = out + 7864320;                                // 7 x 1M fl -> ends 15,204,352
    float* P   = out + 16777216;                               // 1M fl  (tanh'd xqk, [y][2x])
    float* wT  = out + 17825792;                               // 4M fl  [h][m][e][2o] -> 22,020,096
    float* PVG = out + 22020096;                               // 1M fl  [h][m][c][b][e]

    hipLaunchKernelGGL(k0_twiddle, dim3(128),  dim3(256), 0, stream, Whi, Wlo);
    hipLaunchKernelGGL(k1_mfma,    dim3(2048), dim3(256), 0, stream, q, k, Whi, Wlo, Xq, Xk, Pq, Pk);
    hipLaunchKernelGGL(k1_reduce,  dim3(1024), dim3(256), 0, stream, Xq, Pq, Xk, Pk);
    hipLaunchKernelGGL(k2a_p1,     dim3(512),  dim3(256), 0, stream, Xq, Xk, P);
    hipLaunchKernelGGL(k0_basis,   dim3(256),  dim3(256), 0, stream, basis);
    hipLaunchKernelGGL(k2b_p3,     dim3(512),  dim3(256), 0, stream, P, Xk, PVG);
    hipLaunchKernelGGL(kwt,        dim3(512),  dim3(256), 0, stream, w1, w2, wT);
    hipLaunchKernelGGL(k2c_p4,     dim3(512),  dim3(256), 0, stream, PVG, wT, XWThi, XWTlo);
    hipLaunchKernelGGL(k3_mfma,    dim3(2048), dim3(256), 0, stream, basis, XWThi, XWTlo, out);
}